// Round 12
// baseline (6581.528 us; speedup 1.0000x reference)
//
#include <hip/hip_runtime.h>
#include <float.h>
#include <stdint.h>

#pragma clang fp contract(off)

#define BATCH   2
#define N_ANCH  49104
#define NCLS    20
#define MAXDET  300
#define CAP     1024               /* pow2; expected candidates/class ~818 +- 28 */
#define KMAT    512                /* bit-matrix rows (greedy prefix) */
#define MATW    8                  /* KMAT/64 words per row */
#define LMS     9                  /* LDS matrix row stride (u64) — bank spread */
#define NMS_T   512
#define FB_PER  96                 /* ceil(N_ANCH/512) */
#define TSEL    0.59f
#define SCTHR   0.05f
#define NEGF    (-1e9f)
#define HIC     511.0f
#define STDF    0.2f
#define DEAD    (-FLT_MAX)
#define BXL(j)  ((j) + ((j) >> 4))   /* bank-spread padding for bxl */

typedef unsigned long long u64;

// ---- workspace layout (bytes) ----
static constexpr size_t OFF_BOXES = 0;                                    // [B][N][4] f32
static constexpr size_t SZ_BOXES  = (size_t)BATCH * N_ANCH * 4 * 4;
static constexpr size_t OFF_CS    = OFF_BOXES + SZ_BOXES;                 // [B*C][CAP] f32
static constexpr size_t SZ_CS     = (size_t)BATCH * NCLS * CAP * 4;
static constexpr size_t OFF_CI    = OFF_CS + SZ_CS;                       // [B*C][CAP] i32
static constexpr size_t SZ_CI     = SZ_CS;
static constexpr size_t OFF_CNT   = OFF_CI + SZ_CI;                       // [B*C] i32
static constexpr size_t SZ_CNT    = (size_t)BATCH * NCLS * 4;
static constexpr size_t OFF_SS    = OFF_CNT + ((SZ_CNT + 15) & ~(size_t)15); // [B*C][300] f32
static constexpr size_t SZ_SS    = (size_t)BATCH * NCLS * MAXDET * 4;
static constexpr size_t OFF_SI    = OFF_SS + SZ_SS;                       // [B*C][300] i32
static constexpr size_t SZ_SI    = SZ_SS;
static constexpr size_t OFF_SK   = (OFF_SI + SZ_SI + 127) & ~(size_t)127; // [B*C][CAP] u64 sorted keys
static constexpr size_t SZ_SK    = (size_t)BATCH * NCLS * CAP * 8;
static constexpr size_t OFF_SB   = OFF_SK + SZ_SK;                        // [B*C][CAP] float4 sorted boxes
static constexpr size_t SZ_SB    = (size_t)BATCH * NCLS * CAP * 16;
static constexpr size_t OFF_MAT  = OFF_SB + SZ_SB;                        // [B*C][KMAT][MATW] u64 (ROW-major)
static constexpr size_t SZ_MAT   = (size_t)BATCH * NCLS * KMAT * MATW * 8;

// Exact replica of reference IoU decision (full-N fallback):
// iou = inter / (((a_b + area) - inter) + 1e-8); suppress iff iou > 0.5
__device__ __forceinline__ bool iou_gt(float b0, float b1, float b2, float b3,
                                       float ab, float4 e) {
#pragma clang fp contract(off)
  float xx1 = fmaxf(b0, e.x);
  float yy1 = fmaxf(b1, e.y);
  float xx2 = fminf(b2, e.z);
  float yy2 = fminf(b3, e.w);
  float iw = fmaxf(xx2 - xx1, 0.0f);
  float ih = fmaxf(yy2 - yy1, 0.0f);
  float inter = iw * ih;
  float area = (e.z - e.x) * (e.w - e.y);
  float den = ab + area;
  den = den - inter;
  den = den + 1e-8f;
  float iou = inter / den;          // IEEE f32 divide
  return iou > 0.5f;
}

// Bit-exact fast IoU decision (no divide):
// fl(inter/den) > 0.5  <=>  inter/den > 0.5 + 2^-25  (tie rounds to even 0.5)
// (double)inter and (double)den exact; den*(0.5+2^-25) is a 24x25-bit
// product = 49 bits < 53 -> exact comparison. Decision-identical to iou_gt.
// NOTE: bit-SYMMETRIC in (box_r, box_e): inter is commutative (max/min), and
// ab+earea rounds identically under operand swap -> matrix[i][j]==matrix[j][i].
__device__ __forceinline__ bool iou_gt_fast(float b0, float b1, float b2, float b3,
                                            float ab, float4 e, float earea) {
#pragma clang fp contract(off)
  float xx1 = fmaxf(b0, e.x);
  float yy1 = fmaxf(b1, e.y);
  float xx2 = fminf(b2, e.z);
  float yy2 = fminf(b3, e.w);
  float iw = fmaxf(xx2 - xx1, 0.0f);
  float ih = fmaxf(yy2 - yy1, 0.0f);
  float inter = iw * ih;
  float den = ab + earea;
  den = den - inter;
  den = den + 1e-8f;
  return (double)inter > (double)den * 0x1.000001p-1;   // 0.5 + 2^-25
}

// block argmax (score desc, index asc); broadcast via LDS (full-N fallback)
__device__ __forceinline__ void block_argmax(float bs, int bn,
                                             float* red_s, int* red_n,
                                             float* g_s, int* g_n) {
  for (int off = 32; off > 0; off >>= 1) {
    float os = __shfl_down(bs, off);
    int   on = __shfl_down(bn, off);
    if (os > bs || (os == bs && on < bn)) { bs = os; bn = on; }
  }
  int tid = threadIdx.x;
  if ((tid & 63) == 0) { red_s[tid >> 6] = bs; red_n[tid >> 6] = bn; }
  __syncthreads();
  if (tid == 0) {
    float gs = red_s[0]; int gn = red_n[0];
    for (int wv = 1; wv < NMS_T / 64; ++wv) {
      float rs = red_s[wv]; int rn = red_n[wv];
      if (rs > gs || (rs == gs && rn < gn)) { gs = rs; gn = rn; }
    }
    *g_s = gs; *g_n = gn;
  }
  __syncthreads();
}

// K1: decode+clip boxes, gather per-(b,c) candidates with score > TSEL.
__global__ __launch_bounds__(256) void dec_gather(
    const float* __restrict__ anchors, const float* __restrict__ deltas,
    const float* __restrict__ cls, float* __restrict__ boxes,
    float* __restrict__ cand_s, int* __restrict__ cand_i,
    int* __restrict__ cnt) {
#pragma clang fp contract(off)
  __shared__ int lcnt[BATCH * NCLS];
  __shared__ int lbase[BATCH * NCLS];
  const int tid = threadIdx.x;
  const int id = blockIdx.x * 256 + tid;       // id = b*N + n
  const bool live = id < BATCH * N_ANCH;

  int b = 0, n = 0;
  float r[NCLS];
  if (live) {
    b = id / N_ANCH;
    n = id - b * N_ANCH;
    float4 a = ((const float4*)anchors)[id];
    float4 d = ((const float4*)deltas)[id];
    float w = a.z - a.x;
    float h = a.w - a.y;
    float t;
    t = d.x * STDF; float x1 = a.x + t * w;    // (d*0.2f)*w then add — matches np
    t = d.y * STDF; float y1 = a.y + t * h;
    t = d.z * STDF; float x2 = a.z + t * w;
    t = d.w * STDF; float y2 = a.w + t * h;
    float4 bx;
    bx.x = fminf(fmaxf(x1, 0.0f), HIC);
    bx.y = fminf(fmaxf(y1, 0.0f), HIC);
    bx.z = fminf(fmaxf(x2, 0.0f), HIC);
    bx.w = fminf(fmaxf(y2, 0.0f), HIC);
    ((float4*)boxes)[id] = bx;
    const float4* rv = (const float4*)(cls + (size_t)id * NCLS);
#pragma unroll
    for (int k = 0; k < NCLS / 4; ++k) {
      float4 v = rv[k];
      r[k * 4 + 0] = v.x; r[k * 4 + 1] = v.y;
      r[k * 4 + 2] = v.z; r[k * 4 + 3] = v.w;
    }
  }

  if (tid < BATCH * NCLS) lcnt[tid] = 0;
  __syncthreads();

  if (live) {
#pragma unroll
    for (int c = 0; c < NCLS; ++c) {
      if (r[c] > TSEL) atomicAdd(&lcnt[b * NCLS + c], 1);
    }
  }
  __syncthreads();

  if (tid < BATCH * NCLS) {
    int v = lcnt[tid];
    if (v > 0) lbase[tid] = atomicAdd(cnt + tid, v);
    lcnt[tid] = 0;                              // reuse as phase-C cursor
  }
  __syncthreads();

  if (live) {
#pragma unroll
    for (int c = 0; c < NCLS; ++c) {
      float s = r[c];
      if (s > TSEL) {
        int bc = b * NCLS + c;
        int p = atomicAdd(&lcnt[bc], 1);
        int pos = lbase[bc] + p;
        if (pos < CAP) {
          cand_s[(size_t)bc * CAP + pos] = s;
          cand_i[(size_t)bc * CAP + pos] = n;
        }
      }
    }
  }
}

// K2a: per-(b,c) bitonic sort; writes sorted keys + gathered sorted boxes.
__global__ __launch_bounds__(NMS_T) void sort_kernel(
    const float* __restrict__ cand_s, const int* __restrict__ cand_i,
    const int* __restrict__ cnt, const float* __restrict__ boxes,
    u64* __restrict__ skeys, float4* __restrict__ sbox) {
  __shared__ u64 keys[CAP];                    // 8 KB
  const int bc  = blockIdx.x;
  const int tid = threadIdx.x;
  const int count = cnt[bc];
  if (count > CAP) return;                     // overflow -> walk_kernel full-N
  const int b = bc / NCLS;
  const float4* bxs = (const float4*)boxes + (size_t)b * N_ANCH;
  const float* cs = cand_s + (size_t)bc * CAP;
  const int*   ci = cand_i + (size_t)bc * CAP;
  // keys: (score_bits|msb)<<32 | ~idx — descending == greedy argmax order
  for (int g = tid; g < CAP; g += NMS_T) {
    u64 k = 0ull;                              // padding sinks to end
    if (g < count) {
      unsigned int u = __float_as_uint(cs[g]) | 0x80000000u;  // scores > 0
      k = ((u64)u << 32) | (unsigned int)(~ci[g]);
    }
    keys[g] = k;
  }
  __syncthreads();
  for (int kk = 2; kk <= CAP; kk <<= 1) {      // bitonic, descending
    for (int j = kk >> 1; j > 0; j >>= 1) {
#pragma unroll
      for (int p = 0; p < CAP / NMS_T; ++p) {
        int i = tid + p * NMS_T;
        int ixj = i ^ j;
        if (ixj > i) {
          u64 a = keys[i], bk = keys[ixj];
          bool ddir = ((i & kk) == 0);
          if ((a < bk) == ddir) { keys[i] = bk; keys[ixj] = a; }
        }
      }
      __syncthreads();
    }
  }
  u64*    sk = skeys + (size_t)bc * CAP;
  float4* sb = sbox  + (size_t)bc * CAP;
  for (int g = tid; g < count; g += NMS_T) {
    u64 k = keys[g];
    sk[g] = k;
    sb[g] = bxs[(int)(~((unsigned int)k))];    // gather -> coalesced write
  }
}

// K2b: build the 512x512 IoU bit-matrix, 8 row-strips/class (320 blocks).
// ROW-major global layout [bc][r][w]. Diagonal BLOCK words (w==strip) are
// computed in FULL (incl. sub-diagonal bits + self bit) — the walk relies on
// this for the symmetric in-chunk test. Other sub-diagonal / beyond-KM words
// garbage — harmless (decided before use / pre-masked).
__global__ __launch_bounds__(256) void build_kernel(
    const int* __restrict__ cnt, const float4* __restrict__ sbox,
    u64* __restrict__ matg) {
#pragma clang fp contract(off)
  __shared__ float4 cbox[KMAT];                // cols [r0, KM), 8 KB
  const int blk = blockIdx.x;
  const int bc  = blk >> 3;
  const int k   = blk & 7;
  const int count = cnt[bc];
  if (count > CAP) return;
  const int KM = (count < KMAT) ? count : KMAT;
  const int r0 = k * 64;
  if (r0 >= KM) return;
  const int tid = threadIdx.x;
  const float4* sb = sbox + (size_t)bc * CAP;
  const int ncols = KM - r0;
  for (int j = tid; j < ncols; j += 256) cbox[j] = sb[r0 + j];
  __syncthreads();
  const int lane = tid & 63;
  const int g    = tid >> 6;                   // 0..3
  const int r    = r0 + lane;                  // this lane's row
  if (r >= KM) return;
  const float4 rb = cbox[lane];
  const float  ra = (rb.z - rb.x) * (rb.w - rb.y);
  u64* mrow = matg + (size_t)bc * (KMAT * MATW);
  for (int w = k + g; w < MATW; w += 4) {      // w uniform per wave; w>=k
    const int jb = w * 64;
    if (jb >= KM) break;
    const int jmax = (KM - jb < 64) ? (KM - jb) : 64;
    const int cb = jb - r0;                    // >= 0 since w >= k
    u64 bits = 0;
    for (int jj = 0; jj < jmax; ++jj) {
      float4 e = cbox[cb + jj];                // broadcast (uniform address)
      float ea = (e.z - e.x) * (e.w - e.y);
      bits |= (u64)iou_gt_fast(rb.x, rb.y, rb.z, rb.w, ra, e, ea) << jj;
    }
    mrow[(size_t)r * MATW + w] = bits;         // row-major
  }
}

// K2c: prefetch matrix -> LDS (stride-9 rows, bank-spread), then a
// SYMMETRY-BASED wave-parallel walk: per accept the suppression test is each
// lane's LOCAL diagonal word bit ((selfw>>j)&1) gathered by __ballot (vcc) —
// ZERO cross-lane DS ops on the serial chain. Cross-chunk suppression uses
// matrix symmetry too: one independent LDS load per (lane, future chunk).
// Bit-identical to greedy argmax NMS. Tail + full-N fallback unchanged.
__global__ __launch_bounds__(NMS_T) void walk_kernel(
    const float* __restrict__ cls, const float* __restrict__ boxes,
    const int* __restrict__ cnt, const u64* __restrict__ matg,
    const u64* __restrict__ skeys, const float4* __restrict__ sbox,
    float* __restrict__ sel_s, int* __restrict__ sel_i) {
#pragma clang fp contract(off)
  __shared__ u64    lmat[KMAT * LMS];          // 36 KB, [r][w] stride 9; reused
  __shared__ float4 bxl[CAP + CAP / 16];       // tail-only (padded: BXL)
  __shared__ int    apos[MAXDET];
  __shared__ u64    tailmask[8];
  __shared__ int    A_sh;
  __shared__ float  red_s[NMS_T / 64];
  __shared__ int    red_n[NMS_T / 64];
  __shared__ float  g_s;
  __shared__ int    g_n;

  const int bc  = blockIdx.x;
  const int b   = bc / NCLS;
  const int c   = bc - b * NCLS;
  const int tid = threadIdx.x;
  const int count = cnt[bc];
  float* ss = sel_s + (size_t)bc * MAXDET;
  int*   si = sel_i + (size_t)bc * MAXDET;
  const float4* bxs = (const float4*)boxes + (size_t)b * N_ANCH;
  bool fullfb = (count > CAP);

  if (!fullfb) {
    // block-parallel prefetch: matrix -> LDS (coalesced global reads)
    const u64* mg = matg + (size_t)bc * (KMAT * MATW);
    for (int idx = tid; idx < KMAT * MATW; idx += NMS_T) {
      int r = idx >> 3, w = idx & 7;
      lmat[r * LMS + w] = mg[idx];
    }
    __syncthreads();
    const int KM = (count < KMAT) ? count : KMAT;

    // ---- symmetric wave-parallel walk (wave 0) ----
    if (tid < 64) {
      const int lane = tid;
      // deadm bit ch: this lane's candidate in chunk ch is invalid/suppressed
      int deadm = 0;
#pragma unroll
      for (int ch = 0; ch < MATW; ++ch)
        if ((ch << 6) + lane >= KM) deadm |= 1 << ch;
      int A = 0;
#pragma unroll
      for (int ch = 0; ch < MATW; ++ch) {
        u64 cur = __ballot((deadm >> ch) & 1);
        if (cur == ~0ull) continue;            // uniform
        // lane's own diagonal-block word (computed in FULL by build)
        u64 selfw = lmat[(size_t)((ch << 6) + lane) * LMS + ch];
        const int Abase = A;
        u64 acc = 0;
        while (cur != ~0ull) {                 // lockstep; all values uniform
          const int j = __builtin_ctzll(~cur);
          acc |= 1ull << j;
          A++;
          if (A == MAXDET) break;
          // symmetric test: bit j of MY row == bit lane of row j
          bool sup = (selfw >> j) & 1;
          cur |= __ballot(sup) | (1ull << j);  // vcc readout — no DS op
        }
        // lane-parallel emit of this chunk's accepts
        if ((acc >> lane) & 1) {
          int rank = __popcll(acc & ((1ull << lane) - 1ull));
          apos[Abase + rank] = (ch << 6) + lane;
        }
        if (A >= MAXDET) break;                // uniform
        // cross-chunk suppression via symmetry: candidate (ch2,lane) is
        // suppressed by chunk-ch accepts iff (its row's word ch) & acc.
        // 7 independent LDS loads, batched.
#pragma unroll
        for (int ch2 = ch + 1; ch2 < MATW; ++ch2) {
          u64 w = lmat[(size_t)((ch2 << 6) + lane) * LMS + ch];
          if (w & acc) deadm |= 1 << ch2;
        }
      }
      if (lane == 0) A_sh = A;
    }
    __syncthreads();
    const int A0 = A_sh;

    // ---- parallel tail (safety; dead when A0 == 300)
    if (A0 < MAXDET && count > KMAT) {
      const float4* sb = sbox + (size_t)bc * CAP;
      for (int g = tid; g < count; g += NMS_T) bxl[BXL(g)] = sb[g];
      __syncthreads();
      float4* accb = (float4*)lmat;            // lmat no longer needed
      float*  acca = (float*)(accb + MAXDET);
      if (tid < A0) {
        float4 v = bxl[BXL(apos[tid])];
        accb[tid] = v;
        acca[tid] = (v.z - v.x) * (v.w - v.y);
      }
      __syncthreads();
      {
        const int g = KMAT + tid;
        bool alive = (g < count);
        float4 bx = {0.0f, 0.0f, 0.0f, 0.0f};
        float carea = 0.0f;
        if (alive) {
          bx = bxl[BXL(g)];
          carea = (bx.z - bx.x) * (bx.w - bx.y);
        }
        for (int a = 0; a < A0; ++a) {
          if (!alive) break;
          float4 abx = accb[a];
          float  aar = acca[a];
          if (iou_gt_fast(abx.x, abx.y, abx.z, abx.w, aar, bx, carea))
            alive = false;
        }
        u64 bal = __ballot(alive);
        if ((tid & 63) == 0) tailmask[tid >> 6] = bal;
      }
      __syncthreads();
      if (tid < 64) {
        const int lane = tid;
        int A = A0;
        bool done = false;
        for (int w = 0; w < 8 && !done; ++w) {
          u64 mask = tailmask[w];
          if (!mask) continue;
          const int g = KMAT + (w << 6) + lane;
          const bool mine0 = (mask >> lane) & 1;
          float4 bx = {0.0f, 0.0f, 0.0f, 0.0f};
          float carea = 0.0f;
          if (mine0) {
            bx = bxl[BXL(g)];
            carea = (bx.z - bx.x) * (bx.w - bx.y);
          }
          bool alive = mine0;
          for (int a = A0; a < A; ++a) {
            if (!alive) break;
            float4 abx = accb[a];
            float  aar = acca[a];
            if (iou_gt_fast(abx.x, abx.y, abx.z, abx.w, aar, bx, carea))
              alive = false;
          }
          u64 pend = __ballot(alive);
          while (pend) {
            const int jj = __ffsll((long long)pend) - 1;
            pend &= pend - 1;
            const float jx = __shfl(bx.x, jj);
            const float jy = __shfl(bx.y, jj);
            const float jz = __shfl(bx.z, jj);
            const float jw = __shfl(bx.w, jj);
            if (lane == jj) {
              apos[A] = g;
              accb[A] = bx; acca[A] = carea;
            }
            A++;
            if (A == MAXDET) { done = true; break; }
            if (pend) {
              const float jar = (jz - jx) * (jw - jy);
              bool mine = (pend >> lane) & 1;
              bool sup = mine && iou_gt_fast(jx, jy, jz, jw, jar, bx, carea);
              pend &= ~__ballot(sup);
            }
          }
        }
        if (lane == 0) A_sh = A;
      }
      __syncthreads();
    }

    if (A_sh >= MAXDET) {
      if (tid < MAXDET) {                      // parallel emit (keys from L2)
        u64 key = skeys[(size_t)bc * CAP + apos[tid]];
        ss[tid] = __uint_as_float(((unsigned int)(key >> 32)) & 0x7FFFFFFFu);
        si[tid] = (int)(~((unsigned int)key));
      }
      return;
    }
    fullfb = true;
  }

  // ---- exact full-N fallback (correctness insurance)
  {
    const float* crow = cls + ((size_t)b * N_ANCH) * NCLS + c;  // stride NCLS
    const int base = tid * FB_PER;
    float sc[FB_PER];
#pragma unroll
    for (int m = 0; m < FB_PER; ++m) {
      int n = base + m;
      float v = DEAD;
      if (n < N_ANCH) {
        float r = crow[(size_t)n * NCLS];
        v = (r > SCTHR) ? r : NEGF;
      }
      sc[m] = v;
    }
    __syncthreads();
    for (int k = 0; k < MAXDET; ++k) {
      float bs = DEAD; int bn = 0x7FFFFFFF;
#pragma unroll
      for (int m = 0; m < FB_PER; ++m) {
        if (sc[m] > bs) { bs = sc[m]; bn = base + m; }
      }
      block_argmax(bs, bn, red_s, red_n, &g_s, &g_n);
      const float gs = g_s; const int gn = g_n;
      if (tid == 0) { ss[k] = gs; si[k] = gn; }
      float4 w4 = bxs[gn];
      float ab = (w4.z - w4.x) * (w4.w - w4.y);
#pragma unroll
      for (int m = 0; m < FB_PER; ++m) {
        if (sc[m] > NEGF) {
          float4 e = bxs[base + m];
          if (iou_gt(w4.x, w4.y, w4.z, w4.w, ab, e)) sc[m] = NEGF;
        }
      }
    }
  }
}

// K3: stable global top-300 per batch. Pivot prune + exact rank-count.
__global__ __launch_bounds__(512) void topk_kernel(
    const float* __restrict__ sel_s, const int* __restrict__ sel_i,
    const float* __restrict__ boxes, float* __restrict__ out) {
#pragma clang fp contract(off)
  __shared__ u64 keys[NCLS * MAXDET];   // 48 KB
  __shared__ int ccnt[NCLS];
  __shared__ u64 Psh;
  const int b = blockIdx.x;
  const int tid = threadIdx.x;
  const float* ssb = sel_s + (size_t)b * NCLS * MAXDET;
  const int*   sib = sel_i + (size_t)b * NCLS * MAXDET;
  for (int e = tid; e < NCLS * MAXDET; e += 512) {
    unsigned int u = __float_as_uint(ssb[e]);
    u = (u & 0x80000000u) ? ~u : (u | 0x80000000u);    // order-preserving map
    keys[e] = ((u64)u << 32) | (u64)(0xFFFFFFFFu - (unsigned)e);
  }
  __syncthreads();
  if (tid == 0) {
    u64 mn = ~0ull;
    for (int c = 0; c < NCLS; ++c) {
      u64 v = keys[c * MAXDET + 29];
      if (v < mn) mn = v;
    }
    Psh = mn;
  }
  __syncthreads();
  const u64 P = Psh;
  if (tid < NCLS) {
    const u64* kc = keys + tid * MAXDET;
    int lo = 0, hi = MAXDET;
    while (lo < hi) { int mid = (lo + hi) >> 1; if (kc[mid] >= P) lo = mid + 1; else hi = mid; }
    ccnt[tid] = lo;
  }
  __syncthreads();
  for (int e = tid; e < NCLS * MAXDET; e += 512) {
    int c = e / MAXDET;
    int j = e - c * MAXDET;
    if (j >= ccnt[c]) continue;
    u64 ke = keys[e];
    int rank = 0;
    for (int c2 = 0; c2 < NCLS; ++c2) {
      const u64* kc = keys + c2 * MAXDET;
      int lo = 0, hi = ccnt[c2];
      while (lo < hi) {
        int mid = (lo + hi) >> 1;
        if (kc[mid] > ke) lo = mid + 1; else hi = mid;
      }
      rank += lo;
    }
    if (rank < MAXDET) {
      float s = ssb[e];
      int   n = sib[e];
      bool valid = (s > NEGF * 0.5f);
      float4 bx = ((const float4*)boxes)[(size_t)b * N_ANCH + n];
      float* ob = out + ((size_t)b * MAXDET + rank) * 4;
      ob[0] = valid ? bx.x : -1.0f;
      ob[1] = valid ? bx.y : -1.0f;
      ob[2] = valid ? bx.z : -1.0f;
      ob[3] = valid ? bx.w : -1.0f;
      out[(size_t)BATCH * MAXDET * 4 + (size_t)b * MAXDET + rank] = valid ? s : -1.0f;
      out[(size_t)BATCH * MAXDET * 5 + (size_t)b * MAXDET + rank] =
          valid ? (float)c : -1.0f;
    }
  }
}

extern "C" void kernel_launch(void* const* d_in, const int* in_sizes, int n_in,
                              void* d_out, int out_size, void* d_ws, size_t ws_size,
                              hipStream_t stream) {
  (void)in_sizes; (void)n_in; (void)out_size; (void)ws_size;
  const float* anchors = (const float*)d_in[1];
  const float* deltas  = (const float*)d_in[2];
  const float* cls     = (const float*)d_in[3];   // d_in[0] = image: only shape used
  char* ws = (char*)d_ws;
  float*  boxes  = (float*) (ws + OFF_BOXES);
  float*  cand_s = (float*) (ws + OFF_CS);
  int*    cand_i = (int*)   (ws + OFF_CI);
  int*    cnt    = (int*)   (ws + OFF_CNT);
  float*  sel_s  = (float*) (ws + OFF_SS);
  int*    sel_i  = (int*)   (ws + OFF_SI);
  u64*    skeys  = (u64*)   (ws + OFF_SK);
  float4* sbox   = (float4*)(ws + OFF_SB);
  u64*    matg   = (u64*)   (ws + OFF_MAT);

  hipMemsetAsync(cnt, 0, SZ_CNT, stream);   // ws is re-poisoned 0xAA each call

  dec_gather<<<(BATCH * N_ANCH + 255) / 256, 256, 0, stream>>>(
      anchors, deltas, cls, boxes, cand_s, cand_i, cnt);
  sort_kernel<<<BATCH * NCLS, NMS_T, 0, stream>>>(
      cand_s, cand_i, cnt, boxes, skeys, sbox);
  build_kernel<<<BATCH * NCLS * 8, 256, 0, stream>>>(cnt, sbox, matg);
  walk_kernel<<<BATCH * NCLS, NMS_T, 0, stream>>>(
      cls, boxes, cnt, matg, skeys, sbox, sel_s, sel_i);
  topk_kernel<<<BATCH, 512, 0, stream>>>(sel_s, sel_i, boxes, (float*)d_out);
}

// Round 13
// 176.724 us; speedup vs baseline: 37.2418x; 37.2418x over previous
//
#include <hip/hip_runtime.h>
#include <float.h>
#include <stdint.h>

#pragma clang fp contract(off)

#define BATCH   2
#define N_ANCH  49104
#define NCLS    20
#define MAXDET  300
#define CAP     1024               /* pow2; expected candidates/class ~818 +- 28 */
#define KMAT    512                /* bit-matrix rows (greedy prefix) */
#define MATW    8                  /* KMAT/64 words per row */
#define LMS     9                  /* LDS matrix row stride (u64) — bank spread */
#define NMS_T   512
#define FB_PER  96                 /* ceil(N_ANCH/512) */
#define TSEL    0.59f
#define SCTHR   0.05f
#define NEGF    (-1e9f)
#define HIC     511.0f
#define STDF    0.2f
#define DEAD    (-FLT_MAX)
#define BXL(j)  ((j) + ((j) >> 4))   /* bank-spread padding for bxl */

typedef unsigned long long u64;

// ---- workspace layout (bytes) ----
static constexpr size_t OFF_BOXES = 0;                                    // [B][N][4] f32
static constexpr size_t SZ_BOXES  = (size_t)BATCH * N_ANCH * 4 * 4;
static constexpr size_t OFF_CS    = OFF_BOXES + SZ_BOXES;                 // [B*C][CAP] f32
static constexpr size_t SZ_CS     = (size_t)BATCH * NCLS * CAP * 4;
static constexpr size_t OFF_CI    = OFF_CS + SZ_CS;                       // [B*C][CAP] i32
static constexpr size_t SZ_CI     = SZ_CS;
static constexpr size_t OFF_CNT   = OFF_CI + SZ_CI;                       // [B*C] i32
static constexpr size_t SZ_CNT    = (size_t)BATCH * NCLS * 4;
static constexpr size_t OFF_SS    = OFF_CNT + ((SZ_CNT + 15) & ~(size_t)15); // [B*C][300] f32
static constexpr size_t SZ_SS    = (size_t)BATCH * NCLS * MAXDET * 4;
static constexpr size_t OFF_SI    = OFF_SS + SZ_SS;                       // [B*C][300] i32
static constexpr size_t SZ_SI    = SZ_SS;
static constexpr size_t OFF_SK   = (OFF_SI + SZ_SI + 127) & ~(size_t)127; // [B*C][CAP] u64 sorted keys
static constexpr size_t SZ_SK    = (size_t)BATCH * NCLS * CAP * 8;
static constexpr size_t OFF_SB   = OFF_SK + SZ_SK;                        // [B*C][CAP] float4 sorted boxes
static constexpr size_t SZ_SB    = (size_t)BATCH * NCLS * CAP * 16;
static constexpr size_t OFF_MAT  = OFF_SB + SZ_SB;                        // [B*C][KMAT][MATW] u64 (ROW-major)
static constexpr size_t SZ_MAT   = (size_t)BATCH * NCLS * KMAT * MATW * 8;

// Exact replica of reference IoU decision (full-N fallback):
// iou = inter / (((a_b + area) - inter) + 1e-8); suppress iff iou > 0.5
__device__ __forceinline__ bool iou_gt(float b0, float b1, float b2, float b3,
                                       float ab, float4 e) {
#pragma clang fp contract(off)
  float xx1 = fmaxf(b0, e.x);
  float yy1 = fmaxf(b1, e.y);
  float xx2 = fminf(b2, e.z);
  float yy2 = fminf(b3, e.w);
  float iw = fmaxf(xx2 - xx1, 0.0f);
  float ih = fmaxf(yy2 - yy1, 0.0f);
  float inter = iw * ih;
  float area = (e.z - e.x) * (e.w - e.y);
  float den = ab + area;
  den = den - inter;
  den = den + 1e-8f;
  float iou = inter / den;          // IEEE f32 divide
  return iou > 0.5f;
}

// Bit-exact fast IoU decision (no divide):
// fl(inter/den) > 0.5  <=>  inter/den > 0.5 + 2^-25  (tie rounds to even 0.5)
// (double)inter and (double)den exact; den*(0.5+2^-25) is a 24x25-bit
// product = 49 bits < 53 -> exact comparison. Decision-identical to iou_gt.
// Bit-SYMMETRIC in (box_r, box_e): inter commutative, ab+earea rounds the
// same under swap -> matrix[i][j] == matrix[j][i]. The walk RELIES on the
// build writing BOTH triangles (R12 bug: upper-triangle-only build fed
// poison to the symmetric reads -> fallback storm).
__device__ __forceinline__ bool iou_gt_fast(float b0, float b1, float b2, float b3,
                                            float ab, float4 e, float earea) {
#pragma clang fp contract(off)
  float xx1 = fmaxf(b0, e.x);
  float yy1 = fmaxf(b1, e.y);
  float xx2 = fminf(b2, e.z);
  float yy2 = fminf(b3, e.w);
  float iw = fmaxf(xx2 - xx1, 0.0f);
  float ih = fmaxf(yy2 - yy1, 0.0f);
  float inter = iw * ih;
  float den = ab + earea;
  den = den - inter;
  den = den + 1e-8f;
  return (double)inter > (double)den * 0x1.000001p-1;   // 0.5 + 2^-25
}

// block argmax (score desc, index asc); broadcast via LDS (full-N fallback)
__device__ __forceinline__ void block_argmax(float bs, int bn,
                                             float* red_s, int* red_n,
                                             float* g_s, int* g_n) {
  for (int off = 32; off > 0; off >>= 1) {
    float os = __shfl_down(bs, off);
    int   on = __shfl_down(bn, off);
    if (os > bs || (os == bs && on < bn)) { bs = os; bn = on; }
  }
  int tid = threadIdx.x;
  if ((tid & 63) == 0) { red_s[tid >> 6] = bs; red_n[tid >> 6] = bn; }
  __syncthreads();
  if (tid == 0) {
    float gs = red_s[0]; int gn = red_n[0];
    for (int wv = 1; wv < NMS_T / 64; ++wv) {
      float rs = red_s[wv]; int rn = red_n[wv];
      if (rs > gs || (rs == gs && rn < gn)) { gs = rs; gn = rn; }
    }
    *g_s = gs; *g_n = gn;
  }
  __syncthreads();
}

// K1: decode+clip boxes, gather per-(b,c) candidates with score > TSEL.
__global__ __launch_bounds__(256) void dec_gather(
    const float* __restrict__ anchors, const float* __restrict__ deltas,
    const float* __restrict__ cls, float* __restrict__ boxes,
    float* __restrict__ cand_s, int* __restrict__ cand_i,
    int* __restrict__ cnt) {
#pragma clang fp contract(off)
  __shared__ int lcnt[BATCH * NCLS];
  __shared__ int lbase[BATCH * NCLS];
  const int tid = threadIdx.x;
  const int id = blockIdx.x * 256 + tid;       // id = b*N + n
  const bool live = id < BATCH * N_ANCH;

  int b = 0, n = 0;
  float r[NCLS];
  if (live) {
    b = id / N_ANCH;
    n = id - b * N_ANCH;
    float4 a = ((const float4*)anchors)[id];
    float4 d = ((const float4*)deltas)[id];
    float w = a.z - a.x;
    float h = a.w - a.y;
    float t;
    t = d.x * STDF; float x1 = a.x + t * w;    // (d*0.2f)*w then add — matches np
    t = d.y * STDF; float y1 = a.y + t * h;
    t = d.z * STDF; float x2 = a.z + t * w;
    t = d.w * STDF; float y2 = a.w + t * h;
    float4 bx;
    bx.x = fminf(fmaxf(x1, 0.0f), HIC);
    bx.y = fminf(fmaxf(y1, 0.0f), HIC);
    bx.z = fminf(fmaxf(x2, 0.0f), HIC);
    bx.w = fminf(fmaxf(y2, 0.0f), HIC);
    ((float4*)boxes)[id] = bx;
    const float4* rv = (const float4*)(cls + (size_t)id * NCLS);
#pragma unroll
    for (int k = 0; k < NCLS / 4; ++k) {
      float4 v = rv[k];
      r[k * 4 + 0] = v.x; r[k * 4 + 1] = v.y;
      r[k * 4 + 2] = v.z; r[k * 4 + 3] = v.w;
    }
  }

  if (tid < BATCH * NCLS) lcnt[tid] = 0;
  __syncthreads();

  if (live) {
#pragma unroll
    for (int c = 0; c < NCLS; ++c) {
      if (r[c] > TSEL) atomicAdd(&lcnt[b * NCLS + c], 1);
    }
  }
  __syncthreads();

  if (tid < BATCH * NCLS) {
    int v = lcnt[tid];
    if (v > 0) lbase[tid] = atomicAdd(cnt + tid, v);
    lcnt[tid] = 0;                              // reuse as phase-C cursor
  }
  __syncthreads();

  if (live) {
#pragma unroll
    for (int c = 0; c < NCLS; ++c) {
      float s = r[c];
      if (s > TSEL) {
        int bc = b * NCLS + c;
        int p = atomicAdd(&lcnt[bc], 1);
        int pos = lbase[bc] + p;
        if (pos < CAP) {
          cand_s[(size_t)bc * CAP + pos] = s;
          cand_i[(size_t)bc * CAP + pos] = n;
        }
      }
    }
  }
}

// K2a: per-(b,c) bitonic sort; writes sorted keys + gathered sorted boxes.
__global__ __launch_bounds__(NMS_T) void sort_kernel(
    const float* __restrict__ cand_s, const int* __restrict__ cand_i,
    const int* __restrict__ cnt, const float* __restrict__ boxes,
    u64* __restrict__ skeys, float4* __restrict__ sbox) {
  __shared__ u64 keys[CAP];                    // 8 KB
  const int bc  = blockIdx.x;
  const int tid = threadIdx.x;
  const int count = cnt[bc];
  if (count > CAP) return;                     // overflow -> walk_kernel full-N
  const int b = bc / NCLS;
  const float4* bxs = (const float4*)boxes + (size_t)b * N_ANCH;
  const float* cs = cand_s + (size_t)bc * CAP;
  const int*   ci = cand_i + (size_t)bc * CAP;
  // keys: (score_bits|msb)<<32 | ~idx — descending == greedy argmax order
  for (int g = tid; g < CAP; g += NMS_T) {
    u64 k = 0ull;                              // padding sinks to end
    if (g < count) {
      unsigned int u = __float_as_uint(cs[g]) | 0x80000000u;  // scores > 0
      k = ((u64)u << 32) | (unsigned int)(~ci[g]);
    }
    keys[g] = k;
  }
  __syncthreads();
  for (int kk = 2; kk <= CAP; kk <<= 1) {      // bitonic, descending
    for (int j = kk >> 1; j > 0; j >>= 1) {
#pragma unroll
      for (int p = 0; p < CAP / NMS_T; ++p) {
        int i = tid + p * NMS_T;
        int ixj = i ^ j;
        if (ixj > i) {
          u64 a = keys[i], bk = keys[ixj];
          bool ddir = ((i & kk) == 0);
          if ((a < bk) == ddir) { keys[i] = bk; keys[ixj] = a; }
        }
      }
      __syncthreads();
    }
  }
  u64*    sk = skeys + (size_t)bc * CAP;
  float4* sb = sbox  + (size_t)bc * CAP;
  for (int g = tid; g < count; g += NMS_T) {
    u64 k = keys[g];
    sk[g] = k;
    sb[g] = bxs[(int)(~((unsigned int)k))];    // gather -> coalesced write
  }
}

// K2b: build the FULL 512x512 IoU bit-matrix (both triangles), 8 row-strips
// per class (320 blocks). ROW-major [bc][r][w]. Every word the walk reads —
// diagonal selfw AND sub-diagonal transposed words — is genuinely computed.
__global__ __launch_bounds__(256) void build_kernel(
    const int* __restrict__ cnt, const float4* __restrict__ sbox,
    u64* __restrict__ matg) {
#pragma clang fp contract(off)
  __shared__ float4 cbox[KMAT];                // ALL cols [0, KM), 8 KB
  const int blk = blockIdx.x;
  const int bc  = blk >> 3;
  const int k   = blk & 7;
  const int count = cnt[bc];
  if (count > CAP) return;
  const int KM = (count < KMAT) ? count : KMAT;
  const int r0 = k * 64;
  if (r0 >= KM) return;
  const int tid = threadIdx.x;
  const float4* sb = sbox + (size_t)bc * CAP;
  for (int j = tid; j < KM; j += 256) cbox[j] = sb[j];   // full staging
  __syncthreads();
  const int lane = tid & 63;
  const int g    = tid >> 6;                   // 0..3
  const int r    = r0 + lane;                  // this lane's row
  if (r >= KM) return;
  const float4 rb = cbox[r];
  const float  ra = (rb.z - rb.x) * (rb.w - rb.y);
  u64* mrow = matg + (size_t)bc * (KMAT * MATW);
  for (int w = g; w < MATW; w += 4) {          // ALL words (both triangles)
    const int jb = w * 64;
    if (jb >= KM) break;
    const int jmax = (KM - jb < 64) ? (KM - jb) : 64;
    u64 bits = 0;
    for (int jj = 0; jj < jmax; ++jj) {
      float4 e = cbox[jb + jj];                // broadcast (uniform address)
      float ea = (e.z - e.x) * (e.w - e.y);
      bits |= (u64)iou_gt_fast(rb.x, rb.y, rb.z, rb.w, ra, e, ea) << jj;
    }
    mrow[(size_t)r * MATW + w] = bits;         // row-major
  }
}

// K2c: prefetch matrix -> LDS (stride-9 rows), SYMMETRY-BASED wave-parallel
// walk: per accept the suppression test is each lane's LOCAL diagonal word
// bit gathered by __ballot (vcc) — zero cross-lane DS ops on the serial
// chain. Cross-chunk suppression via transposed (now fully built) words:
// 7 independent LDS loads per chunk. Bit-identical to greedy argmax NMS.
__global__ __launch_bounds__(NMS_T) void walk_kernel(
    const float* __restrict__ cls, const float* __restrict__ boxes,
    const int* __restrict__ cnt, const u64* __restrict__ matg,
    const u64* __restrict__ skeys, const float4* __restrict__ sbox,
    float* __restrict__ sel_s, int* __restrict__ sel_i) {
#pragma clang fp contract(off)
  __shared__ u64    lmat[KMAT * LMS];          // 36 KB, [r][w] stride 9; reused
  __shared__ float4 bxl[CAP + CAP / 16];       // tail-only (padded: BXL)
  __shared__ int    apos[MAXDET];
  __shared__ u64    tailmask[8];
  __shared__ int    A_sh;
  __shared__ float  red_s[NMS_T / 64];
  __shared__ int    red_n[NMS_T / 64];
  __shared__ float  g_s;
  __shared__ int    g_n;

  const int bc  = blockIdx.x;
  const int b   = bc / NCLS;
  const int c   = bc - b * NCLS;
  const int tid = threadIdx.x;
  const int count = cnt[bc];
  float* ss = sel_s + (size_t)bc * MAXDET;
  int*   si = sel_i + (size_t)bc * MAXDET;
  const float4* bxs = (const float4*)boxes + (size_t)b * N_ANCH;
  bool fullfb = (count > CAP);

  if (!fullfb) {
    // block-parallel prefetch: matrix -> LDS (coalesced global reads)
    const u64* mg = matg + (size_t)bc * (KMAT * MATW);
    for (int idx = tid; idx < KMAT * MATW; idx += NMS_T) {
      int r = idx >> 3, w = idx & 7;
      lmat[r * LMS + w] = mg[idx];
    }
    __syncthreads();
    const int KM = (count < KMAT) ? count : KMAT;

    // ---- symmetric wave-parallel walk (wave 0) ----
    if (tid < 64) {
      const int lane = tid;
      // deadm bit ch: this lane's candidate in chunk ch is invalid/suppressed
      int deadm = 0;
#pragma unroll
      for (int ch = 0; ch < MATW; ++ch)
        if ((ch << 6) + lane >= KM) deadm |= 1 << ch;
      int A = 0;
#pragma unroll
      for (int ch = 0; ch < MATW; ++ch) {
        u64 cur = __ballot((deadm >> ch) & 1);
        if (cur == ~0ull) continue;            // uniform
        // lane's own diagonal-block word
        u64 selfw = lmat[(size_t)((ch << 6) + lane) * LMS + ch];
        const int Abase = A;
        u64 acc = 0;
        while (cur != ~0ull) {                 // lockstep; all values uniform
          const int j = __builtin_ctzll(~cur);
          acc |= 1ull << j;
          A++;
          if (A == MAXDET) break;
          // symmetric test: bit j of MY row == bit lane of row j
          bool sup = (selfw >> j) & 1;
          cur |= __ballot(sup) | (1ull << j);  // vcc readout — no DS op
        }
        // lane-parallel emit of this chunk's accepts
        if ((acc >> lane) & 1) {
          int rank = __popcll(acc & ((1ull << lane) - 1ull));
          apos[Abase + rank] = (ch << 6) + lane;
        }
        if (A >= MAXDET) break;                // uniform
        // cross-chunk suppression via symmetry (transposed words now built)
#pragma unroll
        for (int ch2 = ch + 1; ch2 < MATW; ++ch2) {
          u64 w = lmat[(size_t)((ch2 << 6) + lane) * LMS + ch];
          if (w & acc) deadm |= 1 << ch2;
        }
      }
      if (lane == 0) A_sh = A;
    }
    __syncthreads();
    const int A0 = A_sh;

    // ---- parallel tail (safety; dead when A0 == 300)
    if (A0 < MAXDET && count > KMAT) {
      const float4* sb = sbox + (size_t)bc * CAP;
      for (int g = tid; g < count; g += NMS_T) bxl[BXL(g)] = sb[g];
      __syncthreads();
      float4* accb = (float4*)lmat;            // lmat no longer needed
      float*  acca = (float*)(accb + MAXDET);
      if (tid < A0) {
        float4 v = bxl[BXL(apos[tid])];
        accb[tid] = v;
        acca[tid] = (v.z - v.x) * (v.w - v.y);
      }
      __syncthreads();
      {
        const int g = KMAT + tid;
        bool alive = (g < count);
        float4 bx = {0.0f, 0.0f, 0.0f, 0.0f};
        float carea = 0.0f;
        if (alive) {
          bx = bxl[BXL(g)];
          carea = (bx.z - bx.x) * (bx.w - bx.y);
        }
        for (int a = 0; a < A0; ++a) {
          if (!alive) break;
          float4 abx = accb[a];
          float  aar = acca[a];
          if (iou_gt_fast(abx.x, abx.y, abx.z, abx.w, aar, bx, carea))
            alive = false;
        }
        u64 bal = __ballot(alive);
        if ((tid & 63) == 0) tailmask[tid >> 6] = bal;
      }
      __syncthreads();
      if (tid < 64) {
        const int lane = tid;
        int A = A0;
        bool done = false;
        for (int w = 0; w < 8 && !done; ++w) {
          u64 mask = tailmask[w];
          if (!mask) continue;
          const int g = KMAT + (w << 6) + lane;
          const bool mine0 = (mask >> lane) & 1;
          float4 bx = {0.0f, 0.0f, 0.0f, 0.0f};
          float carea = 0.0f;
          if (mine0) {
            bx = bxl[BXL(g)];
            carea = (bx.z - bx.x) * (bx.w - bx.y);
          }
          bool alive = mine0;
          for (int a = A0; a < A; ++a) {
            if (!alive) break;
            float4 abx = accb[a];
            float  aar = acca[a];
            if (iou_gt_fast(abx.x, abx.y, abx.z, abx.w, aar, bx, carea))
              alive = false;
          }
          u64 pend = __ballot(alive);
          while (pend) {
            const int jj = __ffsll((long long)pend) - 1;
            pend &= pend - 1;
            const float jx = __shfl(bx.x, jj);
            const float jy = __shfl(bx.y, jj);
            const float jz = __shfl(bx.z, jj);
            const float jw = __shfl(bx.w, jj);
            if (lane == jj) {
              apos[A] = g;
              accb[A] = bx; acca[A] = carea;
            }
            A++;
            if (A == MAXDET) { done = true; break; }
            if (pend) {
              const float jar = (jz - jx) * (jw - jy);
              bool mine = (pend >> lane) & 1;
              bool sup = mine && iou_gt_fast(jx, jy, jz, jw, jar, bx, carea);
              pend &= ~__ballot(sup);
            }
          }
        }
        if (lane == 0) A_sh = A;
      }
      __syncthreads();
    }

    if (A_sh >= MAXDET) {
      if (tid < MAXDET) {                      // parallel emit (keys from L2)
        u64 key = skeys[(size_t)bc * CAP + apos[tid]];
        ss[tid] = __uint_as_float(((unsigned int)(key >> 32)) & 0x7FFFFFFFu);
        si[tid] = (int)(~((unsigned int)key));
      }
      return;
    }
    fullfb = true;
  }

  // ---- exact full-N fallback (correctness insurance)
  {
    const float* crow = cls + ((size_t)b * N_ANCH) * NCLS + c;  // stride NCLS
    const int base = tid * FB_PER;
    float sc[FB_PER];
#pragma unroll
    for (int m = 0; m < FB_PER; ++m) {
      int n = base + m;
      float v = DEAD;
      if (n < N_ANCH) {
        float r = crow[(size_t)n * NCLS];
        v = (r > SCTHR) ? r : NEGF;
      }
      sc[m] = v;
    }
    __syncthreads();
    for (int k = 0; k < MAXDET; ++k) {
      float bs = DEAD; int bn = 0x7FFFFFFF;
#pragma unroll
      for (int m = 0; m < FB_PER; ++m) {
        if (sc[m] > bs) { bs = sc[m]; bn = base + m; }
      }
      block_argmax(bs, bn, red_s, red_n, &g_s, &g_n);
      const float gs = g_s; const int gn = g_n;
      if (tid == 0) { ss[k] = gs; si[k] = gn; }
      float4 w4 = bxs[gn];
      float ab = (w4.z - w4.x) * (w4.w - w4.y);
#pragma unroll
      for (int m = 0; m < FB_PER; ++m) {
        if (sc[m] > NEGF) {
          float4 e = bxs[base + m];
          if (iou_gt(w4.x, w4.y, w4.z, w4.w, ab, e)) sc[m] = NEGF;
        }
      }
    }
  }
}

// K3: stable global top-300 per batch. Pivot prune + exact rank-count.
__global__ __launch_bounds__(512) void topk_kernel(
    const float* __restrict__ sel_s, const int* __restrict__ sel_i,
    const float* __restrict__ boxes, float* __restrict__ out) {
#pragma clang fp contract(off)
  __shared__ u64 keys[NCLS * MAXDET];   // 48 KB
  __shared__ int ccnt[NCLS];
  __shared__ u64 Psh;
  const int b = blockIdx.x;
  const int tid = threadIdx.x;
  const float* ssb = sel_s + (size_t)b * NCLS * MAXDET;
  const int*   sib = sel_i + (size_t)b * NCLS * MAXDET;
  for (int e = tid; e < NCLS * MAXDET; e += 512) {
    unsigned int u = __float_as_uint(ssb[e]);
    u = (u & 0x80000000u) ? ~u : (u | 0x80000000u);    // order-preserving map
    keys[e] = ((u64)u << 32) | (u64)(0xFFFFFFFFu - (unsigned)e);
  }
  __syncthreads();
  if (tid == 0) {
    u64 mn = ~0ull;
    for (int c = 0; c < NCLS; ++c) {
      u64 v = keys[c * MAXDET + 29];
      if (v < mn) mn = v;
    }
    Psh = mn;
  }
  __syncthreads();
  const u64 P = Psh;
  if (tid < NCLS) {
    const u64* kc = keys + tid * MAXDET;
    int lo = 0, hi = MAXDET;
    while (lo < hi) { int mid = (lo + hi) >> 1; if (kc[mid] >= P) lo = mid + 1; else hi = mid; }
    ccnt[tid] = lo;
  }
  __syncthreads();
  for (int e = tid; e < NCLS * MAXDET; e += 512) {
    int c = e / MAXDET;
    int j = e - c * MAXDET;
    if (j >= ccnt[c]) continue;
    u64 ke = keys[e];
    int rank = 0;
    for (int c2 = 0; c2 < NCLS; ++c2) {
      const u64* kc = keys + c2 * MAXDET;
      int lo = 0, hi = ccnt[c2];
      while (lo < hi) {
        int mid = (lo + hi) >> 1;
        if (kc[mid] > ke) lo = mid + 1; else hi = mid;
      }
      rank += lo;
    }
    if (rank < MAXDET) {
      float s = ssb[e];
      int   n = sib[e];
      bool valid = (s > NEGF * 0.5f);
      float4 bx = ((const float4*)boxes)[(size_t)b * N_ANCH + n];
      float* ob = out + ((size_t)b * MAXDET + rank) * 4;
      ob[0] = valid ? bx.x : -1.0f;
      ob[1] = valid ? bx.y : -1.0f;
      ob[2] = valid ? bx.z : -1.0f;
      ob[3] = valid ? bx.w : -1.0f;
      out[(size_t)BATCH * MAXDET * 4 + (size_t)b * MAXDET + rank] = valid ? s : -1.0f;
      out[(size_t)BATCH * MAXDET * 5 + (size_t)b * MAXDET + rank] =
          valid ? (float)c : -1.0f;
    }
  }
}

extern "C" void kernel_launch(void* const* d_in, const int* in_sizes, int n_in,
                              void* d_out, int out_size, void* d_ws, size_t ws_size,
                              hipStream_t stream) {
  (void)in_sizes; (void)n_in; (void)out_size; (void)ws_size;
  const float* anchors = (const float*)d_in[1];
  const float* deltas  = (const float*)d_in[2];
  const float* cls     = (const float*)d_in[3];   // d_in[0] = image: only shape used
  char* ws = (char*)d_ws;
  float*  boxes  = (float*) (ws + OFF_BOXES);
  float*  cand_s = (float*) (ws + OFF_CS);
  int*    cand_i = (int*)   (ws + OFF_CI);
  int*    cnt    = (int*)   (ws + OFF_CNT);
  float*  sel_s  = (float*) (ws + OFF_SS);
  int*    sel_i  = (int*)   (ws + OFF_SI);
  u64*    skeys  = (u64*)   (ws + OFF_SK);
  float4* sbox   = (float4*)(ws + OFF_SB);
  u64*    matg   = (u64*)   (ws + OFF_MAT);

  hipMemsetAsync(cnt, 0, SZ_CNT, stream);   // ws is re-poisoned 0xAA each call

  dec_gather<<<(BATCH * N_ANCH + 255) / 256, 256, 0, stream>>>(
      anchors, deltas, cls, boxes, cand_s, cand_i, cnt);
  sort_kernel<<<BATCH * NCLS, NMS_T, 0, stream>>>(
      cand_s, cand_i, cnt, boxes, skeys, sbox);
  build_kernel<<<BATCH * NCLS * 8, 256, 0, stream>>>(cnt, sbox, matg);
  walk_kernel<<<BATCH * NCLS, NMS_T, 0, stream>>>(
      cls, boxes, cnt, matg, skeys, sbox, sel_s, sel_i);
  topk_kernel<<<BATCH, 512, 0, stream>>>(sel_s, sel_i, boxes, (float*)d_out);
}

// Round 14
// 159.566 us; speedup vs baseline: 41.2463x; 1.1075x over previous
//
#include <hip/hip_runtime.h>
#include <float.h>
#include <stdint.h>

#pragma clang fp contract(off)

#define BATCH   2
#define N_ANCH  49104
#define NCLS    20
#define MAXDET  300
#define CAP     1024               /* pow2; expected candidates/class ~818 +- 28 */
#define KMAT    512                /* bit-matrix rows (greedy prefix) */
#define MATW    8                  /* KMAT/64 words per row */
#define LMS     9                  /* LDS matrix row stride (u64) — bank spread */
#define NMS_T   512
#define FB_PER  96                 /* ceil(N_ANCH/512) */
#define TSEL    0.59f
#define SCTHR   0.05f
#define NEGF    (-1e9f)
#define HIC     511.0f
#define STDF    0.2f
#define DEAD    (-FLT_MAX)
#define BXL(j)  ((j) + ((j) >> 4))   /* bank-spread padding for bxl */

typedef unsigned long long u64;

// ---- workspace layout (bytes) ----
static constexpr size_t OFF_BOXES = 0;                                    // [B][N][4] f32
static constexpr size_t SZ_BOXES  = (size_t)BATCH * N_ANCH * 4 * 4;
static constexpr size_t OFF_CS    = OFF_BOXES + SZ_BOXES;                 // [B*C][CAP] f32
static constexpr size_t SZ_CS     = (size_t)BATCH * NCLS * CAP * 4;
static constexpr size_t OFF_CI    = OFF_CS + SZ_CS;                       // [B*C][CAP] i32
static constexpr size_t SZ_CI     = SZ_CS;
static constexpr size_t OFF_CNT   = OFF_CI + SZ_CI;                       // [B*C] i32
static constexpr size_t SZ_CNT    = (size_t)BATCH * NCLS * 4;
static constexpr size_t OFF_SS    = OFF_CNT + ((SZ_CNT + 15) & ~(size_t)15); // [B*C][300] f32
static constexpr size_t SZ_SS    = (size_t)BATCH * NCLS * MAXDET * 4;
static constexpr size_t OFF_SI    = OFF_SS + SZ_SS;                       // [B*C][300] i32
static constexpr size_t SZ_SI    = SZ_SS;
static constexpr size_t OFF_SK   = (OFF_SI + SZ_SI + 127) & ~(size_t)127; // [B*C][CAP] u64 sorted keys
static constexpr size_t SZ_SK    = (size_t)BATCH * NCLS * CAP * 8;
static constexpr size_t OFF_SB   = OFF_SK + SZ_SK;                        // [B*C][CAP] float4 sorted boxes
static constexpr size_t SZ_SB    = (size_t)BATCH * NCLS * CAP * 16;
static constexpr size_t OFF_MAT  = OFF_SB + SZ_SB;                        // [B*C][KMAT][MATW] u64 (ROW-major)
static constexpr size_t SZ_MAT   = (size_t)BATCH * NCLS * KMAT * MATW * 8;

// Exact replica of reference IoU decision (full-N fallback):
// iou = inter / (((a_b + area) - inter) + 1e-8); suppress iff iou > 0.5
__device__ __forceinline__ bool iou_gt(float b0, float b1, float b2, float b3,
                                       float ab, float4 e) {
#pragma clang fp contract(off)
  float xx1 = fmaxf(b0, e.x);
  float yy1 = fmaxf(b1, e.y);
  float xx2 = fminf(b2, e.z);
  float yy2 = fminf(b3, e.w);
  float iw = fmaxf(xx2 - xx1, 0.0f);
  float ih = fmaxf(yy2 - yy1, 0.0f);
  float inter = iw * ih;
  float area = (e.z - e.x) * (e.w - e.y);
  float den = ab + area;
  den = den - inter;
  den = den + 1e-8f;
  float iou = inter / den;          // IEEE f32 divide
  return iou > 0.5f;
}

// Bit-exact fast IoU decision (no divide):
// fl(inter/den) > 0.5  <=>  inter/den > 0.5 + 2^-25  (tie rounds to even 0.5)
// (double)inter and (double)den exact; den*(0.5+2^-25) is a 24x25-bit
// product = 49 bits < 53 -> exact comparison. Decision-identical to iou_gt.
// Bit-SYMMETRIC in (box_r, box_e) -> matrix[i][j] == matrix[j][i]; the build
// writes BOTH triangles (R12 lesson: symmetric reads of unwritten words =
// poison = fallback storm).
__device__ __forceinline__ bool iou_gt_fast(float b0, float b1, float b2, float b3,
                                            float ab, float4 e, float earea) {
#pragma clang fp contract(off)
  float xx1 = fmaxf(b0, e.x);
  float yy1 = fmaxf(b1, e.y);
  float xx2 = fminf(b2, e.z);
  float yy2 = fminf(b3, e.w);
  float iw = fmaxf(xx2 - xx1, 0.0f);
  float ih = fmaxf(yy2 - yy1, 0.0f);
  float inter = iw * ih;
  float den = ab + earea;
  den = den - inter;
  den = den + 1e-8f;
  return (double)inter > (double)den * 0x1.000001p-1;   // 0.5 + 2^-25
}

// block argmax (score desc, index asc); broadcast via LDS (full-N fallback)
__device__ __forceinline__ void block_argmax(float bs, int bn,
                                             float* red_s, int* red_n,
                                             float* g_s, int* g_n) {
  for (int off = 32; off > 0; off >>= 1) {
    float os = __shfl_down(bs, off);
    int   on = __shfl_down(bn, off);
    if (os > bs || (os == bs && on < bn)) { bs = os; bn = on; }
  }
  int tid = threadIdx.x;
  if ((tid & 63) == 0) { red_s[tid >> 6] = bs; red_n[tid >> 6] = bn; }
  __syncthreads();
  if (tid == 0) {
    float gs = red_s[0]; int gn = red_n[0];
    for (int wv = 1; wv < NMS_T / 64; ++wv) {
      float rs = red_s[wv]; int rn = red_n[wv];
      if (rs > gs || (rs == gs && rn < gn)) { gs = rs; gn = rn; }
    }
    *g_s = gs; *g_n = gn;
  }
  __syncthreads();
}

// K1: decode+clip boxes, gather per-(b,c) candidates with score > TSEL.
__global__ __launch_bounds__(256) void dec_gather(
    const float* __restrict__ anchors, const float* __restrict__ deltas,
    const float* __restrict__ cls, float* __restrict__ boxes,
    float* __restrict__ cand_s, int* __restrict__ cand_i,
    int* __restrict__ cnt) {
#pragma clang fp contract(off)
  __shared__ int lcnt[BATCH * NCLS];
  __shared__ int lbase[BATCH * NCLS];
  const int tid = threadIdx.x;
  const int id = blockIdx.x * 256 + tid;       // id = b*N + n
  const bool live = id < BATCH * N_ANCH;

  int b = 0, n = 0;
  float r[NCLS];
  if (live) {
    b = id / N_ANCH;
    n = id - b * N_ANCH;
    float4 a = ((const float4*)anchors)[id];
    float4 d = ((const float4*)deltas)[id];
    float w = a.z - a.x;
    float h = a.w - a.y;
    float t;
    t = d.x * STDF; float x1 = a.x + t * w;    // (d*0.2f)*w then add — matches np
    t = d.y * STDF; float y1 = a.y + t * h;
    t = d.z * STDF; float x2 = a.z + t * w;
    t = d.w * STDF; float y2 = a.w + t * h;
    float4 bx;
    bx.x = fminf(fmaxf(x1, 0.0f), HIC);
    bx.y = fminf(fmaxf(y1, 0.0f), HIC);
    bx.z = fminf(fmaxf(x2, 0.0f), HIC);
    bx.w = fminf(fmaxf(y2, 0.0f), HIC);
    ((float4*)boxes)[id] = bx;
    const float4* rv = (const float4*)(cls + (size_t)id * NCLS);
#pragma unroll
    for (int k = 0; k < NCLS / 4; ++k) {
      float4 v = rv[k];
      r[k * 4 + 0] = v.x; r[k * 4 + 1] = v.y;
      r[k * 4 + 2] = v.z; r[k * 4 + 3] = v.w;
    }
  }

  if (tid < BATCH * NCLS) lcnt[tid] = 0;
  __syncthreads();

  if (live) {
#pragma unroll
    for (int c = 0; c < NCLS; ++c) {
      if (r[c] > TSEL) atomicAdd(&lcnt[b * NCLS + c], 1);
    }
  }
  __syncthreads();

  if (tid < BATCH * NCLS) {
    int v = lcnt[tid];
    if (v > 0) lbase[tid] = atomicAdd(cnt + tid, v);
    lcnt[tid] = 0;                              // reuse as phase-C cursor
  }
  __syncthreads();

  if (live) {
#pragma unroll
    for (int c = 0; c < NCLS; ++c) {
      float s = r[c];
      if (s > TSEL) {
        int bc = b * NCLS + c;
        int p = atomicAdd(&lcnt[bc], 1);
        int pos = lbase[bc] + p;
        if (pos < CAP) {
          cand_s[(size_t)bc * CAP + pos] = s;
          cand_i[(size_t)bc * CAP + pos] = n;
        }
      }
    }
  }
}

// K2a: per-(b,c) bitonic sort; writes sorted keys + gathered sorted boxes.
__global__ __launch_bounds__(NMS_T) void sort_kernel(
    const float* __restrict__ cand_s, const int* __restrict__ cand_i,
    const int* __restrict__ cnt, const float* __restrict__ boxes,
    u64* __restrict__ skeys, float4* __restrict__ sbox) {
  __shared__ u64 keys[CAP];                    // 8 KB
  const int bc  = blockIdx.x;
  const int tid = threadIdx.x;
  const int count = cnt[bc];
  if (count > CAP) return;                     // overflow -> walk_kernel full-N
  const int b = bc / NCLS;
  const float4* bxs = (const float4*)boxes + (size_t)b * N_ANCH;
  const float* cs = cand_s + (size_t)bc * CAP;
  const int*   ci = cand_i + (size_t)bc * CAP;
  // keys: (score_bits|msb)<<32 | ~idx — descending == greedy argmax order
  for (int g = tid; g < CAP; g += NMS_T) {
    u64 k = 0ull;                              // padding sinks to end
    if (g < count) {
      unsigned int u = __float_as_uint(cs[g]) | 0x80000000u;  // scores > 0
      k = ((u64)u << 32) | (unsigned int)(~ci[g]);
    }
    keys[g] = k;
  }
  __syncthreads();
  for (int kk = 2; kk <= CAP; kk <<= 1) {      // bitonic, descending
    for (int j = kk >> 1; j > 0; j >>= 1) {
#pragma unroll
      for (int p = 0; p < CAP / NMS_T; ++p) {
        int i = tid + p * NMS_T;
        int ixj = i ^ j;
        if (ixj > i) {
          u64 a = keys[i], bk = keys[ixj];
          bool ddir = ((i & kk) == 0);
          if ((a < bk) == ddir) { keys[i] = bk; keys[ixj] = a; }
        }
      }
      __syncthreads();
    }
  }
  u64*    sk = skeys + (size_t)bc * CAP;
  float4* sb = sbox  + (size_t)bc * CAP;
  for (int g = tid; g < count; g += NMS_T) {
    u64 k = keys[g];
    sk[g] = k;
    sb[g] = bxs[(int)(~((unsigned int)k))];    // gather -> coalesced write
  }
}

// K2b: build the FULL 512x512 IoU bit-matrix (both triangles), 8 row-strips
// per class (320 blocks). ROW-major [bc][r][w].
__global__ __launch_bounds__(256) void build_kernel(
    const int* __restrict__ cnt, const float4* __restrict__ sbox,
    u64* __restrict__ matg) {
#pragma clang fp contract(off)
  __shared__ float4 cbox[KMAT];                // ALL cols [0, KM), 8 KB
  const int blk = blockIdx.x;
  const int bc  = blk >> 3;
  const int k   = blk & 7;
  const int count = cnt[bc];
  if (count > CAP) return;
  const int KM = (count < KMAT) ? count : KMAT;
  const int r0 = k * 64;
  if (r0 >= KM) return;
  const int tid = threadIdx.x;
  const float4* sb = sbox + (size_t)bc * CAP;
  for (int j = tid; j < KM; j += 256) cbox[j] = sb[j];   // full staging
  __syncthreads();
  const int lane = tid & 63;
  const int g    = tid >> 6;                   // 0..3
  const int r    = r0 + lane;                  // this lane's row
  if (r >= KM) return;
  const float4 rb = cbox[r];
  const float  ra = (rb.z - rb.x) * (rb.w - rb.y);
  u64* mrow = matg + (size_t)bc * (KMAT * MATW);
  for (int w = g; w < MATW; w += 4) {          // ALL words (both triangles)
    const int jb = w * 64;
    if (jb >= KM) break;
    const int jmax = (KM - jb < 64) ? (KM - jb) : 64;
    u64 bits = 0;
    for (int jj = 0; jj < jmax; ++jj) {
      float4 e = cbox[jb + jj];                // broadcast (uniform address)
      float ea = (e.z - e.x) * (e.w - e.y);
      bits |= (u64)iou_gt_fast(rb.x, rb.y, rb.z, rb.w, ra, e, ea) << jj;
    }
    mrow[(size_t)r * MATW + w] = bits;         // row-major
  }
}

// K2c: symmetric wave-parallel walk (see R13) + tail safety + full-N fallback.
__global__ __launch_bounds__(NMS_T) void walk_kernel(
    const float* __restrict__ cls, const float* __restrict__ boxes,
    const int* __restrict__ cnt, const u64* __restrict__ matg,
    const u64* __restrict__ skeys, const float4* __restrict__ sbox,
    float* __restrict__ sel_s, int* __restrict__ sel_i) {
#pragma clang fp contract(off)
  __shared__ u64    lmat[KMAT * LMS];          // 36 KB, [r][w] stride 9; reused
  __shared__ float4 bxl[CAP + CAP / 16];       // tail-only (padded: BXL)
  __shared__ int    apos[MAXDET];
  __shared__ u64    tailmask[8];
  __shared__ int    A_sh;
  __shared__ float  red_s[NMS_T / 64];
  __shared__ int    red_n[NMS_T / 64];
  __shared__ float  g_s;
  __shared__ int    g_n;

  const int bc  = blockIdx.x;
  const int b   = bc / NCLS;
  const int c   = bc - b * NCLS;
  const int tid = threadIdx.x;
  const int count = cnt[bc];
  float* ss = sel_s + (size_t)bc * MAXDET;
  int*   si = sel_i + (size_t)bc * MAXDET;
  const float4* bxs = (const float4*)boxes + (size_t)b * N_ANCH;
  bool fullfb = (count > CAP);

  if (!fullfb) {
    // block-parallel prefetch: matrix -> LDS (coalesced global reads)
    const u64* mg = matg + (size_t)bc * (KMAT * MATW);
    for (int idx = tid; idx < KMAT * MATW; idx += NMS_T) {
      int r = idx >> 3, w = idx & 7;
      lmat[r * LMS + w] = mg[idx];
    }
    __syncthreads();
    const int KM = (count < KMAT) ? count : KMAT;

    // ---- symmetric wave-parallel walk (wave 0) ----
    if (tid < 64) {
      const int lane = tid;
      int deadm = 0;
#pragma unroll
      for (int ch = 0; ch < MATW; ++ch)
        if ((ch << 6) + lane >= KM) deadm |= 1 << ch;
      int A = 0;
#pragma unroll
      for (int ch = 0; ch < MATW; ++ch) {
        u64 cur = __ballot((deadm >> ch) & 1);
        if (cur == ~0ull) continue;            // uniform
        u64 selfw = lmat[(size_t)((ch << 6) + lane) * LMS + ch];
        const int Abase = A;
        u64 acc = 0;
        while (cur != ~0ull) {                 // lockstep; all values uniform
          const int j = __builtin_ctzll(~cur);
          acc |= 1ull << j;
          A++;
          if (A == MAXDET) break;
          bool sup = (selfw >> j) & 1;         // symmetric test, local bit
          cur |= __ballot(sup) | (1ull << j);  // vcc readout — no DS op
        }
        if ((acc >> lane) & 1) {               // lane-parallel emit
          int rank = __popcll(acc & ((1ull << lane) - 1ull));
          apos[Abase + rank] = (ch << 6) + lane;
        }
        if (A >= MAXDET) break;                // uniform
#pragma unroll
        for (int ch2 = ch + 1; ch2 < MATW; ++ch2) {
          u64 w = lmat[(size_t)((ch2 << 6) + lane) * LMS + ch];
          if (w & acc) deadm |= 1 << ch2;
        }
      }
      if (lane == 0) A_sh = A;
    }
    __syncthreads();
    const int A0 = A_sh;

    // ---- parallel tail (safety; dead when A0 == 300)
    if (A0 < MAXDET && count > KMAT) {
      const float4* sb = sbox + (size_t)bc * CAP;
      for (int g = tid; g < count; g += NMS_T) bxl[BXL(g)] = sb[g];
      __syncthreads();
      float4* accb = (float4*)lmat;            // lmat no longer needed
      float*  acca = (float*)(accb + MAXDET);
      if (tid < A0) {
        float4 v = bxl[BXL(apos[tid])];
        accb[tid] = v;
        acca[tid] = (v.z - v.x) * (v.w - v.y);
      }
      __syncthreads();
      {
        const int g = KMAT + tid;
        bool alive = (g < count);
        float4 bx = {0.0f, 0.0f, 0.0f, 0.0f};
        float carea = 0.0f;
        if (alive) {
          bx = bxl[BXL(g)];
          carea = (bx.z - bx.x) * (bx.w - bx.y);
        }
        for (int a = 0; a < A0; ++a) {
          if (!alive) break;
          float4 abx = accb[a];
          float  aar = acca[a];
          if (iou_gt_fast(abx.x, abx.y, abx.z, abx.w, aar, bx, carea))
            alive = false;
        }
        u64 bal = __ballot(alive);
        if ((tid & 63) == 0) tailmask[tid >> 6] = bal;
      }
      __syncthreads();
      if (tid < 64) {
        const int lane = tid;
        int A = A0;
        bool done = false;
        for (int w = 0; w < 8 && !done; ++w) {
          u64 mask = tailmask[w];
          if (!mask) continue;
          const int g = KMAT + (w << 6) + lane;
          const bool mine0 = (mask >> lane) & 1;
          float4 bx = {0.0f, 0.0f, 0.0f, 0.0f};
          float carea = 0.0f;
          if (mine0) {
            bx = bxl[BXL(g)];
            carea = (bx.z - bx.x) * (bx.w - bx.y);
          }
          bool alive = mine0;
          for (int a = A0; a < A; ++a) {
            if (!alive) break;
            float4 abx = accb[a];
            float  aar = acca[a];
            if (iou_gt_fast(abx.x, abx.y, abx.z, abx.w, aar, bx, carea))
              alive = false;
          }
          u64 pend = __ballot(alive);
          while (pend) {
            const int jj = __ffsll((long long)pend) - 1;
            pend &= pend - 1;
            const float jx = __shfl(bx.x, jj);
            const float jy = __shfl(bx.y, jj);
            const float jz = __shfl(bx.z, jj);
            const float jw = __shfl(bx.w, jj);
            if (lane == jj) {
              apos[A] = g;
              accb[A] = bx; acca[A] = carea;
            }
            A++;
            if (A == MAXDET) { done = true; break; }
            if (pend) {
              const float jar = (jz - jx) * (jw - jy);
              bool mine = (pend >> lane) & 1;
              bool sup = mine && iou_gt_fast(jx, jy, jz, jw, jar, bx, carea);
              pend &= ~__ballot(sup);
            }
          }
        }
        if (lane == 0) A_sh = A;
      }
      __syncthreads();
    }

    if (A_sh >= MAXDET) {
      if (tid < MAXDET) {                      // parallel emit (keys from L2)
        u64 key = skeys[(size_t)bc * CAP + apos[tid]];
        ss[tid] = __uint_as_float(((unsigned int)(key >> 32)) & 0x7FFFFFFFu);
        si[tid] = (int)(~((unsigned int)key));
      }
      return;
    }
    fullfb = true;
  }

  // ---- exact full-N fallback (correctness insurance)
  {
    const float* crow = cls + ((size_t)b * N_ANCH) * NCLS + c;  // stride NCLS
    const int base = tid * FB_PER;
    float sc[FB_PER];
#pragma unroll
    for (int m = 0; m < FB_PER; ++m) {
      int n = base + m;
      float v = DEAD;
      if (n < N_ANCH) {
        float r = crow[(size_t)n * NCLS];
        v = (r > SCTHR) ? r : NEGF;
      }
      sc[m] = v;
    }
    __syncthreads();
    for (int k = 0; k < MAXDET; ++k) {
      float bs = DEAD; int bn = 0x7FFFFFFF;
#pragma unroll
      for (int m = 0; m < FB_PER; ++m) {
        if (sc[m] > bs) { bs = sc[m]; bn = base + m; }
      }
      block_argmax(bs, bn, red_s, red_n, &g_s, &g_n);
      const float gs = g_s; const int gn = g_n;
      if (tid == 0) { ss[k] = gs; si[k] = gn; }
      float4 w4 = bxs[gn];
      float ab = (w4.z - w4.x) * (w4.w - w4.y);
#pragma unroll
      for (int m = 0; m < FB_PER; ++m) {
        if (sc[m] > NEGF) {
          float4 e = bxs[base + m];
          if (iou_gt(w4.x, w4.y, w4.z, w4.w, ab, e)) sc[m] = NEGF;
        }
      }
    }
  }
}

// K3: stable global top-300 per batch. Pivot filter (P = min_c key[c][29]
// -> >=600 survivors, top-300 subset of survivors) + ballot compaction +
// BROADCAST rank-count (uniform-address LDS reads, no dependent chains).
// Old binary-search rank path retained as exact fallback if survivors >1024.
__global__ __launch_bounds__(512) void topk_kernel(
    const float* __restrict__ sel_s, const int* __restrict__ sel_i,
    const float* __restrict__ boxes, float* __restrict__ out) {
#pragma clang fp contract(off)
  __shared__ u64 keys[NCLS * MAXDET];   // 48 KB
  __shared__ u64 ckey[1024];            // 8 KB
  __shared__ int cidx[1024];            // 4 KB
  __shared__ int ccnt[NCLS];
  __shared__ unsigned long long Psh;
  __shared__ int cntsh;
  const int b = blockIdx.x;
  const int tid = threadIdx.x;
  const float* ssb = sel_s + (size_t)b * NCLS * MAXDET;
  const int*   sib = sel_i + (size_t)b * NCLS * MAXDET;
  for (int e = tid; e < NCLS * MAXDET; e += 512) {
    unsigned int u = __float_as_uint(ssb[e]);
    u = (u & 0x80000000u) ? ~u : (u | 0x80000000u);    // order-preserving map
    keys[e] = ((u64)u << 32) | (u64)(0xFFFFFFFFu - (unsigned)e);
  }
  if (tid == 0) { Psh = ~0ull; cntsh = 0; }
  __syncthreads();
  if (tid < NCLS) atomicMin(&Psh, keys[tid * MAXDET + 29]);
  __syncthreads();
  const u64 P = Psh;
  // ballot compaction of survivors (key >= P); order irrelevant (unique keys)
  for (int e = tid; e < NCLS * MAXDET; e += 512) {
    bool keep = keys[e] >= P;
    u64 bal = __ballot(keep);
    const int lane = tid & 63;
    int base = 0;
    int nk = __popcll(bal);
    if (lane == 0 && nk) base = atomicAdd(&cntsh, nk);
    base = __shfl(base, 0);
    if (keep) {
      int p = base + __popcll(bal & ((1ull << lane) - 1ull));
      if (p < 1024) { ckey[p] = keys[e]; cidx[p] = e; }
    }
  }
  __syncthreads();
  const int total = cntsh;
  if (total <= 1024) {
    // broadcast rank-count: all threads read ckey[a] at the same a ->
    // LDS broadcast, pipelined, zero dependent chains
    for (int s = tid; s < total; s += 512) {
      const u64 mk = ckey[s];
      int rank = 0;
      for (int a = 0; a < total; ++a) rank += (ckey[a] > mk) ? 1 : 0;
      if (rank < MAXDET) {
        int e = cidx[s];
        float sc = ssb[e];
        int   n  = sib[e];
        int   cc = e / MAXDET;
        bool valid = (sc > NEGF * 0.5f);
        float4 bx = ((const float4*)boxes)[(size_t)b * N_ANCH + n];
        float* ob = out + ((size_t)b * MAXDET + rank) * 4;
        ob[0] = valid ? bx.x : -1.0f;
        ob[1] = valid ? bx.y : -1.0f;
        ob[2] = valid ? bx.z : -1.0f;
        ob[3] = valid ? bx.w : -1.0f;
        out[(size_t)BATCH * MAXDET * 4 + (size_t)b * MAXDET + rank] =
            valid ? sc : -1.0f;
        out[(size_t)BATCH * MAXDET * 5 + (size_t)b * MAXDET + rank] =
            valid ? (float)cc : -1.0f;
      }
    }
    return;
  }
  // ---- fallback: exact rank-count via per-class binary searches
  if (tid < NCLS) {
    const u64* kc = keys + tid * MAXDET;
    int lo = 0, hi = MAXDET;
    while (lo < hi) { int mid = (lo + hi) >> 1; if (kc[mid] >= P) lo = mid + 1; else hi = mid; }
    ccnt[tid] = lo;
  }
  __syncthreads();
  for (int e = tid; e < NCLS * MAXDET; e += 512) {
    int c = e / MAXDET;
    int j = e - c * MAXDET;
    if (j >= ccnt[c]) continue;
    u64 ke = keys[e];
    int rank = 0;
    for (int c2 = 0; c2 < NCLS; ++c2) {
      const u64* kc = keys + c2 * MAXDET;
      int lo = 0, hi = ccnt[c2];
      while (lo < hi) {
        int mid = (lo + hi) >> 1;
        if (kc[mid] > ke) lo = mid + 1; else hi = mid;
      }
      rank += lo;
    }
    if (rank < MAXDET) {
      float s = ssb[e];
      int   n = sib[e];
      bool valid = (s > NEGF * 0.5f);
      float4 bx = ((const float4*)boxes)[(size_t)b * N_ANCH + n];
      float* ob = out + ((size_t)b * MAXDET + rank) * 4;
      ob[0] = valid ? bx.x : -1.0f;
      ob[1] = valid ? bx.y : -1.0f;
      ob[2] = valid ? bx.z : -1.0f;
      ob[3] = valid ? bx.w : -1.0f;
      out[(size_t)BATCH * MAXDET * 4 + (size_t)b * MAXDET + rank] = valid ? s : -1.0f;
      out[(size_t)BATCH * MAXDET * 5 + (size_t)b * MAXDET + rank] =
          valid ? (float)c : -1.0f;
    }
  }
}

extern "C" void kernel_launch(void* const* d_in, const int* in_sizes, int n_in,
                              void* d_out, int out_size, void* d_ws, size_t ws_size,
                              hipStream_t stream) {
  (void)in_sizes; (void)n_in; (void)out_size; (void)ws_size;
  const float* anchors = (const float*)d_in[1];
  const float* deltas  = (const float*)d_in[2];
  const float* cls     = (const float*)d_in[3];   // d_in[0] = image: only shape used
  char* ws = (char*)d_ws;
  float*  boxes  = (float*) (ws + OFF_BOXES);
  float*  cand_s = (float*) (ws + OFF_CS);
  int*    cand_i = (int*)   (ws + OFF_CI);
  int*    cnt    = (int*)   (ws + OFF_CNT);
  float*  sel_s  = (float*) (ws + OFF_SS);
  int*    sel_i  = (int*)   (ws + OFF_SI);
  u64*    skeys  = (u64*)   (ws + OFF_SK);
  float4* sbox   = (float4*)(ws + OFF_SB);
  u64*    matg   = (u64*)   (ws + OFF_MAT);

  hipMemsetAsync(cnt, 0, SZ_CNT, stream);   // ws is re-poisoned 0xAA each call

  dec_gather<<<(BATCH * N_ANCH + 255) / 256, 256, 0, stream>>>(
      anchors, deltas, cls, boxes, cand_s, cand_i, cnt);
  sort_kernel<<<BATCH * NCLS, NMS_T, 0, stream>>>(
      cand_s, cand_i, cnt, boxes, skeys, sbox);
  build_kernel<<<BATCH * NCLS * 8, 256, 0, stream>>>(cnt, sbox, matg);
  walk_kernel<<<BATCH * NCLS, NMS_T, 0, stream>>>(
      cls, boxes, cnt, matg, skeys, sbox, sel_s, sel_i);
  topk_kernel<<<BATCH, 512, 0, stream>>>(sel_s, sel_i, boxes, (float*)d_out);
}